// Round 1
// baseline (777.791 us; speedup 1.0000x reference)
//
#include <hip/hip_runtime.h>

// Sizes (fixed for this problem):
// x:      (8, 256, 64, 64) fp32
// w_adj:  (18, 256, 1, 1), b_adj: (18)
// w_off:  (18, 1, 3, 3),   b_off: (18)
// w_def:  (256, 256, 3, 3)
// out:    (8, 256, 64, 64) fp32
//
// ws layout (floats):
//   xchan : 8*18*64*64 = 589824
//   off   : 589824
//   w_t   : 9*256*256  = 589824   (w_t[k][c][co] = w_def[co][c][k])
// total 7,077,888 bytes

#define NPLANE 4096   // 64*64

// ---------------- weight transpose: w_def (O,C,3,3) -> w_t (k,c,o) ----------
__global__ __launch_bounds__(256) void k_reorder(const float* __restrict__ w_def,
                                                 float* __restrict__ w_t) {
    int idx = blockIdx.x * 256 + threadIdx.x;       // over 9*256*256
    int co = idx & 255;
    int c  = (idx >> 8) & 255;
    int k  = idx >> 16;
    w_t[idx] = w_def[co * 2304 + c * 9 + k];
}

// ---------------- 1x1 conv: xchan[n,oc,h,w] = b + sum_c x*w ----------------
__global__ __launch_bounds__(128) void k_xchan(const float* __restrict__ x,
                                               const float* __restrict__ w_adj,
                                               const float* __restrict__ b_adj,
                                               float* __restrict__ xchan) {
    __shared__ float wsh[18 * 256];
    int t = threadIdx.x;
    for (int i = t; i < 18 * 256; i += 128) wsh[i] = w_adj[i];
    __syncthreads();
    int gp  = blockIdx.x * 128 + t;       // global pixel among N*4096
    int n   = gp >> 12;
    int pix = gp & 4095;
    const float* xp = x + (n << 20) + pix;   // n*256*4096
    float acc[18];
#pragma unroll
    for (int o = 0; o < 18; ++o) acc[o] = b_adj[o];
    for (int c = 0; c < 256; ++c) {
        float xv = xp[c << 12];
#pragma unroll
        for (int o = 0; o < 18; ++o) acc[o] = fmaf(xv, wsh[(o << 8) + c], acc[o]);
    }
    float* op = xchan + n * (18 * NPLANE) + pix;
#pragma unroll
    for (int o = 0; o < 18; ++o) op[o << 12] = acc[o];
}

// ---------------- depthwise 3x3 conv (groups=18), pad=1 --------------------
__global__ __launch_bounds__(256) void k_off(const float* __restrict__ xchan,
                                             const float* __restrict__ w_off,
                                             const float* __restrict__ b_off,
                                             float* __restrict__ off) {
    int idx = blockIdx.x * 256 + threadIdx.x;   // over 8*18*4096
    int pix = idx & 4095;
    int w = pix & 63, h = pix >> 6;
    int rest = idx >> 12;
    int oc = rest % 18;
    const float* wp  = w_off + oc * 9;
    const float* src = xchan + (idx & ~4095);
    float acc = b_off[oc];
#pragma unroll
    for (int i = 0; i < 3; ++i) {
        int hh = h - 1 + i;
        if ((unsigned)hh >= 64u) continue;
#pragma unroll
        for (int j = 0; j < 3; ++j) {
            int ww = w - 1 + j;
            if ((unsigned)ww >= 64u) continue;
            acc = fmaf(src[(hh << 6) + ww], wp[i * 3 + j], acc);
        }
    }
    off[idx] = acc;
}

// ---------------- deformable conv as implicit GEMM -------------------------
// block: 256 threads; tile = 64 pixels (one image row) x 128 couts
// thread microtile: 4 pixels x 8 couts
__global__ __launch_bounds__(256) void k_deform(const float* __restrict__ x,
                                                const float* __restrict__ off,
                                                const float* __restrict__ w_t,
                                                float* __restrict__ out) {
    __shared__ float colS[16][64];
    __shared__ float wS[16][128];
    __shared__ int   sy0[64], sx0[64];
    __shared__ float swy[64], swx[64];

    int t   = threadIdx.x;
    int n   = blockIdx.x >> 6;
    int h   = blockIdx.x & 63;
    int co0 = blockIdx.y << 7;

    float acc[4][8];
#pragma unroll
    for (int i = 0; i < 4; ++i)
#pragma unroll
        for (int j = 0; j < 8; ++j) acc[i][j] = 0.f;

    int tp = t & 15;         // pixel group (pixels tp*4 .. +3)
    int tc = t >> 4;         // cout group  (couts tc*8 .. +7)
    int cc_b = t >> 4;       // channel within chunk for col build
    int p0_b = (t & 15) << 2;

    const float* xn = x + (n << 20);

    for (int k = 0; k < 9; ++k) {
        // stage bilinear positions for this k (safe: previous chunk's pos
        // readers finished before its second barrier; inner loop reads only
        // colS/wS)
        if (t < 64) {
            const float* offp = off + ((n * 18 + 2 * k) << 12) + (h << 6);
            float oy = offp[t];
            float ox = offp[4096 + t];
            float py = (float)(h - 1 + k / 3) + oy;
            float px = (float)(t - 1 + k % 3) + ox;
            float fy = floorf(py), fx = floorf(px);
            sy0[t] = (int)fy;
            sx0[t] = (int)fx;
            swy[t] = py - fy;
            swx[t] = px - fx;
        }
        for (int c0 = 0; c0 < 256; c0 += 16) {
            __syncthreads();
            // ---- build col chunk: 16 channels x 64 pixels, bilinear ----
            {
                const float* base = xn + ((c0 + cc_b) << 12);
#pragma unroll
                for (int u = 0; u < 4; ++u) {
                    int p = p0_b + u;
                    int y0 = sy0[p], x0 = sx0[p];
                    float wy = swy[p], wx = swx[p];
                    float v00 = 0.f, v01 = 0.f, v10 = 0.f, v11 = 0.f;
                    bool oky0 = (unsigned)y0 < 64u;
                    bool oky1 = (unsigned)(y0 + 1) < 64u;
                    bool okx0 = (unsigned)x0 < 64u;
                    bool okx1 = (unsigned)(x0 + 1) < 64u;
                    int r0 = (y0 << 6) + x0;
                    if (oky0 && okx0) v00 = base[r0];
                    if (oky0 && okx1) v01 = base[r0 + 1];
                    if (oky1 && okx0) v10 = base[r0 + 64];
                    if (oky1 && okx1) v11 = base[r0 + 65];
                    colS[cc_b][p] = (v00 * (1.f - wx) + v01 * wx) * (1.f - wy) +
                                    (v10 * (1.f - wx) + v11 * wx) * wy;
                }
            }
            // ---- stage weight chunk: wS[cc][co], coalesced from w_t ----
            {
                const float* wt = w_t + (k << 16) + (c0 << 8) + co0;
#pragma unroll
                for (int i = 0; i < 2; ++i) {
                    int fi = i * 256 + t;        // float4 index, 0..511
                    int cc = fi >> 5;            // 32 float4 per cc-row
                    int cf = (fi & 31) << 2;
                    *(float4*)&wS[cc][cf] = *(const float4*)&wt[(cc << 8) + cf];
                }
            }
            __syncthreads();
            // ---- 16-step fp32 outer-product accumulate ----
#pragma unroll
            for (int kk = 0; kk < 16; ++kk) {
                float4 cv = *(const float4*)&colS[kk][tp << 2];
                float4 w0 = *(const float4*)&wS[kk][tc << 3];
                float4 w1 = *(const float4*)&wS[kk][(tc << 3) + 4];
                float cva[4] = {cv.x, cv.y, cv.z, cv.w};
                float wa[8]  = {w0.x, w0.y, w0.z, w0.w, w1.x, w1.y, w1.z, w1.w};
#pragma unroll
                for (int i = 0; i < 4; ++i)
#pragma unroll
                    for (int j = 0; j < 8; ++j)
                        acc[i][j] = fmaf(cva[i], wa[j], acc[i][j]);
            }
        }
    }

    // ---- epilogue: out[n, co0+tc*8+j, h, tp*4 + i] ----
    int ob = (n << 20) + ((co0 + (tc << 3)) << 12) + (h << 6) + (tp << 2);
#pragma unroll
    for (int j = 0; j < 8; ++j) {
        float4 v = {acc[0][j], acc[1][j], acc[2][j], acc[3][j]};
        *(float4*)&out[ob + (j << 12)] = v;
    }
}

extern "C" void kernel_launch(void* const* d_in, const int* in_sizes, int n_in,
                              void* d_out, int out_size, void* d_ws, size_t ws_size,
                              hipStream_t stream) {
    const float* x     = (const float*)d_in[0];
    const float* w_adj = (const float*)d_in[1];
    const float* b_adj = (const float*)d_in[2];
    const float* w_off = (const float*)d_in[3];
    const float* b_off = (const float*)d_in[4];
    const float* w_def = (const float*)d_in[5];
    float* out = (float*)d_out;

    float* xchan = (float*)d_ws;
    float* off   = xchan + 589824;
    float* w_t   = off + 589824;

    k_reorder<<<2304, 256, 0, stream>>>(w_def, w_t);
    k_xchan<<<256, 128, 0, stream>>>(x, w_adj, b_adj, xchan);
    k_off<<<2304, 256, 0, stream>>>(xchan, w_off, b_off, off);
    k_deform<<<dim3(512, 2), 256, 0, stream>>>(x, off, w_t, out);
}

// Round 2
// 329.543 us; speedup vs baseline: 2.3602x; 2.3602x over previous
//
#include <hip/hip_runtime.h>

// Sizes (fixed):
// x: (8,256,64,64) f32 | w_adj: (18,256,1,1) | b_adj: (18)
// w_off: (18,1,3,3) | b_off: (18) | w_def: (256,256,3,3)
// out: (8,256,64,64) f32
//
// Implicit GEMM: out[cout][pix] = sum_{K=tap*256+c} W[cout][K] * col[K][pix]
// M=256 couts, N=32768 pixels, K=2304  -> 38.7 GFLOP -> bf16 MFMA.
//
// ws layout (bytes):
//   xchan f32 : [0,          2359296)
//   off   f32 : [2359296,    4718592)
//   wfrag bf16: [4718592,    5898240)   72 ksteps x 16 couttiles x 64 lanes x 8
//   col   bf16: [5898240,  156893184)   8 n x 72 ksteps x 256 pixtiles x 64 x 8
// Fallback (ws too small): old fp32 path, w_t f32 at [4718592, 7077888).

typedef __attribute__((ext_vector_type(8))) short short8v;
typedef __attribute__((ext_vector_type(4))) float f32x4;

#define NPLANE 4096

__device__ inline unsigned bf16_1(float a) {
    unsigned u = __float_as_uint(a);
    u += 0x7fffu + ((u >> 16) & 1u);
    return u >> 16;
}
__device__ inline unsigned bf16_pair(float a, float b) {
    unsigned ua = __float_as_uint(a); ua += 0x7fffu + ((ua >> 16) & 1u);
    unsigned ub = __float_as_uint(b); ub += 0x7fffu + ((ub >> 16) & 1u);
    return (ua >> 16) | (ub & 0xffff0000u);
}

// ---------------- 1x1 conv: xchan[n,oc,pix] ----------------
__global__ __launch_bounds__(128) void k_xchan(const float* __restrict__ x,
                                               const float* __restrict__ w_adj,
                                               const float* __restrict__ b_adj,
                                               float* __restrict__ xchan) {
    __shared__ float wsh[18 * 256];
    int t = threadIdx.x;
    for (int i = t; i < 18 * 256; i += 128) wsh[i] = w_adj[i];
    __syncthreads();
    int gp  = blockIdx.x * 128 + t;
    int n   = gp >> 12;
    int pix = gp & 4095;
    const float* xp = x + (n << 20) + pix;
    float acc[18];
#pragma unroll
    for (int o = 0; o < 18; ++o) acc[o] = b_adj[o];
    for (int c = 0; c < 256; ++c) {
        float xv = xp[c << 12];
#pragma unroll
        for (int o = 0; o < 18; ++o) acc[o] = fmaf(xv, wsh[(o << 8) + c], acc[o]);
    }
    float* op = xchan + n * (18 * NPLANE) + pix;
#pragma unroll
    for (int o = 0; o < 18; ++o) op[o << 12] = acc[o];
}

// ---------------- depthwise 3x3 (groups=18), pad=1 ----------------
__global__ __launch_bounds__(256) void k_off(const float* __restrict__ xchan,
                                             const float* __restrict__ w_off,
                                             const float* __restrict__ b_off,
                                             float* __restrict__ off) {
    int idx = blockIdx.x * 256 + threadIdx.x;
    int pix = idx & 4095;
    int w = pix & 63, h = pix >> 6;
    int rest = idx >> 12;
    int oc = rest % 18;
    const float* wp  = w_off + oc * 9;
    const float* src = xchan + (idx & ~4095);
    float acc = b_off[oc];
#pragma unroll
    for (int i = 0; i < 3; ++i) {
        int hh = h - 1 + i;
        if ((unsigned)hh >= 64u) continue;
#pragma unroll
        for (int j = 0; j < 3; ++j) {
            int ww = w - 1 + j;
            if ((unsigned)ww >= 64u) continue;
            acc = fmaf(src[(hh << 6) + ww], wp[i * 3 + j], acc);
        }
    }
    off[idx] = acc;
}

// ---------------- weight -> MFMA A-fragment layout (bf16) ----------------
// wfrag[kstep][ct][lane][e]: cout = ct*16 + (lane&15); k32 = (lane>>4)*8 + e
// K = kstep*32 + k32 maps to tap = kstep>>3, c = (kstep&7)*32 + k32
__global__ __launch_bounds__(256) void k_wfrag(const float* __restrict__ w_def,
                                               ushort* __restrict__ wfrag) {
    int idx = blockIdx.x * 256 + threadIdx.x;   // over 589824
    int e     = idx & 7;
    int lane  = (idx >> 3) & 63;
    int ct    = (idx >> 9) & 15;
    int kstep = idx >> 13;
    int cout = ct * 16 + (lane & 15);
    int c    = ((kstep & 7) << 5) + ((lane >> 4) << 3) + e;
    int tap  = kstep >> 3;
    float v = w_def[cout * 2304 + c * 9 + tap];
    wfrag[idx] = (ushort)bf16_1(v);
}

// ---------------- bilinear sampler -> col in MFMA B-fragment layout ------
// col[n][kstep][tile][lane][8]: pix = tile*16 + (lane&15),
// c = (kstep&7)*32 + (lane>>4)*8 + e, tap = kstep>>3
__global__ __launch_bounds__(256) void k_sample(const float* __restrict__ x,
                                                const float* __restrict__ off,
                                                ushort* __restrict__ col) {
    int b = blockIdx.x;              // 8 * 72 * 64
    int n  = b / 4608;
    int r  = b - n * 4608;
    int kstep = r >> 6;
    int tb    = r & 63;
    int t    = threadIdx.x;
    int tile = tb * 4 + (t >> 6);
    int lane = t & 63;

    int pix = tile * 16 + (lane & 15);
    int tap = kstep >> 3;
    int c0  = ((kstep & 7) << 5) + ((lane >> 4) << 3);

    const float* offp = off + (((n * 18 + 2 * tap) << 12) + pix);
    float oy = offp[0];
    float ox = offp[NPLANE];

    float py = (float)((pix >> 6) - 1 + tap / 3) + oy;
    float px = (float)((pix & 63) - 1 + tap % 3) + ox;
    float fy = floorf(py), fx = floorf(px);
    int y0 = (int)fy, x0 = (int)fx;
    float wy1 = py - fy, wx1 = px - fx;
    float wy0 = 1.f - wy1, wx0 = 1.f - wx1;
    float ay0 = ((unsigned)y0       < 64u) ? wy0 : 0.f;
    float ay1 = ((unsigned)(y0 + 1) < 64u) ? wy1 : 0.f;
    float ax0 = ((unsigned)x0       < 64u) ? wx0 : 0.f;
    float ax1 = ((unsigned)(x0 + 1) < 64u) ? wx1 : 0.f;
    float w00 = ay0 * ax0, w01 = ay0 * ax1, w10 = ay1 * ax0, w11 = ay1 * ax1;
    int yc0 = min(max(y0, 0), 63),     yc1 = min(max(y0 + 1, 0), 63);
    int xc0 = min(max(x0, 0), 63),     xc1 = min(max(x0 + 1, 0), 63);
    int o00 = (yc0 << 6) + xc0, o01 = (yc0 << 6) + xc1;
    int o10 = (yc1 << 6) + xc0, o11 = (yc1 << 6) + xc1;

    const float* pch = x + ((size_t)n << 20) + ((size_t)c0 << 12);
    unsigned rr[4];
#pragma unroll
    for (int e2 = 0; e2 < 4; ++e2) {
        float v0 = w00 * pch[o00] + w01 * pch[o01] + w10 * pch[o10] + w11 * pch[o11];
        pch += NPLANE;
        float v1 = w00 * pch[o00] + w01 * pch[o01] + w10 * pch[o10] + w11 * pch[o11];
        pch += NPLANE;
        rr[e2] = bf16_pair(v0, v1);
    }
    size_t frag = (size_t)(n * 72 + kstep) * 256 + tile;
    uint4* dst = (uint4*)(col + frag * 512 + lane * 8);
    *dst = make_uint4(rr[0], rr[1], rr[2], rr[3]);
}

// ---------------- MFMA GEMM: no LDS, no barriers ----------------
// block = 4 waves; block covers 64 pixels (4 frag tiles) x all 256 couts
// wave w: couts [w*64, w*64+64) -> acc[4 pixtiles][4 couttiles]
__global__ __launch_bounds__(256) void k_gemm(const ushort* __restrict__ col,
                                              const ushort* __restrict__ wfrag,
                                              float* __restrict__ out) {
    int t = threadIdx.x;
    int wv = t >> 6, lane = t & 63;
    int n  = blockIdx.x >> 6;
    int tb = (blockIdx.x & 63) << 2;    // base 16-pix tile within plane

    const ushort* ca = col + ((size_t)(n * 72) * 256 + tb) * 512 + lane * 8;
    const ushort* wb = wfrag + (size_t)(wv * 4) * 512 + lane * 8;

    f32x4 acc[4][4] = {};

#pragma unroll 2
    for (int ks = 0; ks < 72; ++ks) {
        short8v a[4], bb[4];
        const ushort* cak = ca + (size_t)ks * (256 * 512);
        const ushort* wbk = wb + (size_t)ks * (16 * 512);
#pragma unroll
        for (int i = 0; i < 4; ++i) a[i]  = *(const short8v*)(cak + i * 512);
#pragma unroll
        for (int j = 0; j < 4; ++j) bb[j] = *(const short8v*)(wbk + j * 512);
#pragma unroll
        for (int i = 0; i < 4; ++i)
#pragma unroll
            for (int j = 0; j < 4; ++j)
                acc[i][j] = __builtin_amdgcn_mfma_f32_16x16x32_bf16(
                    bb[j], a[i], acc[i][j], 0, 0, 0);
    }

    // D layout: col = lane&15 (pix), row = (lane>>4)*4 + r (cout)
    int pixb = tb << 4;
    int cl = lane & 15;
    int ch = (lane >> 4) << 2;
    float* outn = out + ((size_t)n << 20);
#pragma unroll
    for (int i = 0; i < 4; ++i) {
        int pix = pixb + (i << 4) + cl;
#pragma unroll
        for (int j = 0; j < 4; ++j) {
            int cout = (wv << 6) + (j << 4) + ch;
            float* op = outn + ((size_t)cout << 12) + pix;
#pragma unroll
            for (int rr = 0; rr < 4; ++rr) op[(size_t)rr << 12] = acc[i][j][rr];
        }
    }
}

// ================= fallback fp32 path (ws too small) =================
__global__ __launch_bounds__(256) void k_reorder(const float* __restrict__ w_def,
                                                 float* __restrict__ w_t) {
    int idx = blockIdx.x * 256 + threadIdx.x;
    int co = idx & 255;
    int c  = (idx >> 8) & 255;
    int k  = idx >> 16;
    w_t[idx] = w_def[co * 2304 + c * 9 + k];
}

__global__ __launch_bounds__(256) void k_deform(const float* __restrict__ x,
                                                const float* __restrict__ off,
                                                const float* __restrict__ w_t,
                                                float* __restrict__ out) {
    __shared__ float colS[16][64];
    __shared__ float wS[16][128];
    __shared__ int   sy0[64], sx0[64];
    __shared__ float swy[64], swx[64];
    int t   = threadIdx.x;
    int n   = blockIdx.x >> 6;
    int h   = blockIdx.x & 63;
    int co0 = blockIdx.y << 7;
    float acc[4][8];
#pragma unroll
    for (int i = 0; i < 4; ++i)
#pragma unroll
        for (int j = 0; j < 8; ++j) acc[i][j] = 0.f;
    int tp = t & 15, tc = t >> 4;
    int cc_b = t >> 4, p0_b = (t & 15) << 2;
    const float* xn = x + (n << 20);
    for (int k = 0; k < 9; ++k) {
        if (t < 64) {
            const float* offp = off + ((n * 18 + 2 * k) << 12) + (h << 6);
            float oy = offp[t];
            float ox = offp[4096 + t];
            float py = (float)(h - 1 + k / 3) + oy;
            float px = (float)(t - 1 + k % 3) + ox;
            float fy = floorf(py), fx = floorf(px);
            sy0[t] = (int)fy; sx0[t] = (int)fx;
            swy[t] = py - fy; swx[t] = px - fx;
        }
        for (int c0 = 0; c0 < 256; c0 += 16) {
            __syncthreads();
            const float* base = xn + ((c0 + cc_b) << 12);
#pragma unroll
            for (int u = 0; u < 4; ++u) {
                int p = p0_b + u;
                int y0 = sy0[p], x0 = sx0[p];
                float wy = swy[p], wx = swx[p];
                float v00 = 0.f, v01 = 0.f, v10 = 0.f, v11 = 0.f;
                bool oky0 = (unsigned)y0 < 64u, oky1 = (unsigned)(y0 + 1) < 64u;
                bool okx0 = (unsigned)x0 < 64u, okx1 = (unsigned)(x0 + 1) < 64u;
                int r0 = (y0 << 6) + x0;
                if (oky0 && okx0) v00 = base[r0];
                if (oky0 && okx1) v01 = base[r0 + 1];
                if (oky1 && okx0) v10 = base[r0 + 64];
                if (oky1 && okx1) v11 = base[r0 + 65];
                colS[cc_b][p] = (v00 * (1.f - wx) + v01 * wx) * (1.f - wy) +
                                (v10 * (1.f - wx) + v11 * wx) * wy;
            }
            const float* wt = w_t + (k << 16) + (c0 << 8) + co0;
#pragma unroll
            for (int i = 0; i < 2; ++i) {
                int fi = i * 256 + t;
                int cc = fi >> 5;
                int cf = (fi & 31) << 2;
                *(float4*)&wS[cc][cf] = *(const float4*)&wt[(cc << 8) + cf];
            }
            __syncthreads();
#pragma unroll
            for (int kk = 0; kk < 16; ++kk) {
                float4 cv = *(const float4*)&colS[kk][tp << 2];
                float4 w0 = *(const float4*)&wS[kk][tc << 3];
                float4 w1 = *(const float4*)&wS[kk][(tc << 3) + 4];
                float cva[4] = {cv.x, cv.y, cv.z, cv.w};
                float wa[8]  = {w0.x, w0.y, w0.z, w0.w, w1.x, w1.y, w1.z, w1.w};
#pragma unroll
                for (int i = 0; i < 4; ++i)
#pragma unroll
                    for (int j = 0; j < 8; ++j)
                        acc[i][j] = fmaf(cva[i], wa[j], acc[i][j]);
            }
        }
    }
    int ob = (n << 20) + ((co0 + (tc << 3)) << 12) + (h << 6) + (tp << 2);
#pragma unroll
    for (int j = 0; j < 8; ++j) {
        float4 v = {acc[0][j], acc[1][j], acc[2][j], acc[3][j]};
        *(float4*)&out[ob + (j << 12)] = v;
    }
}

extern "C" void kernel_launch(void* const* d_in, const int* in_sizes, int n_in,
                              void* d_out, int out_size, void* d_ws, size_t ws_size,
                              hipStream_t stream) {
    const float* x     = (const float*)d_in[0];
    const float* w_adj = (const float*)d_in[1];
    const float* b_adj = (const float*)d_in[2];
    const float* w_off = (const float*)d_in[3];
    const float* b_off = (const float*)d_in[4];
    const float* w_def = (const float*)d_in[5];
    float* out = (float*)d_out;

    char* ws = (char*)d_ws;
    float* xchan = (float*)ws;                          // 2359296 B
    float* off   = (float*)(ws + 2359296);              // 2359296 B

    k_xchan<<<256, 128, 0, stream>>>(x, w_adj, b_adj, xchan);
    k_off<<<2304, 256, 0, stream>>>(xchan, w_off, b_off, off);

    const size_t NEED = 156893184;
    if (ws_size >= NEED) {
        ushort* wfrag = (ushort*)(ws + 4718592);        // 1179648 B
        ushort* col   = (ushort*)(ws + 5898240);        // 150994944 B
        k_wfrag<<<2304, 256, 0, stream>>>(w_def, wfrag);
        k_sample<<<36864, 256, 0, stream>>>(x, off, col);
        k_gemm<<<512, 256, 0, stream>>>(col, wfrag, out);
    } else {
        float* w_t = (float*)(ws + 4718592);
        k_reorder<<<2304, 256, 0, stream>>>(w_def, w_t);
        k_deform<<<dim3(512, 2), 256, 0, stream>>>(x, off, w_t, out);
    }
}

// Round 3
// 267.078 us; speedup vs baseline: 2.9122x; 1.2339x over previous
//
#include <hip/hip_runtime.h>

// Sizes (fixed):
// x: (8,256,64,64) f32 | w_adj: (18,256,1,1) | b_adj: (18)
// w_off: (18,1,3,3) | b_off: (18) | w_def: (256,256,3,3)
// out: (8,256,64,64) f32
//
// Implicit GEMM: out[cout][pix] = sum_{K=tap*256+c} W[cout][K] * col[K][pix]
// M=256, N=32768, K=2304 -> 38.7 GFLOP -> bf16 MFMA.
//
// ws layout (bytes):
//   xchan f32 : [0,        2359296)
//   off   f32 : [2359296,  4718592)
//   wfrag bf16: [4718592,  5898240)
//   xquad 8B  : [5898240,  75120640)   8n x 256c x 65 x 65 quads (padded border)
//   col   bf16: [75120640, 150618112)  HALF batch: 4n x 72ks x 256tiles x 64 x 8
// Batch processed in two halves (n 0..3, 4..7) to fit ws.
// Fallback (ws too small): fp32 path, w_t f32 at [4718592, 7077888).

typedef __attribute__((ext_vector_type(8))) short short8v;
typedef __attribute__((ext_vector_type(4))) float f32x4;

#define NPLANE 4096
#define QPITCH 4225   // 65*65

__device__ inline unsigned bf16_1(float a) {
    unsigned u = __float_as_uint(a);
    u += 0x7fffu + ((u >> 16) & 1u);
    return u >> 16;
}
__device__ inline unsigned bf16_pair(float a, float b) {
    unsigned ua = __float_as_uint(a); ua += 0x7fffu + ((ua >> 16) & 1u);
    unsigned ub = __float_as_uint(b); ub += 0x7fffu + ((ub >> 16) & 1u);
    return (ua >> 16) | (ub & 0xffff0000u);
}
__device__ inline float bl(unsigned u) { return __uint_as_float(u << 16); }
__device__ inline float bh(unsigned u) { return __uint_as_float(u & 0xffff0000u); }

// ---------------- 1x1 conv: xchan[n,oc,pix] ----------------
__global__ __launch_bounds__(128) void k_xchan(const float* __restrict__ x,
                                               const float* __restrict__ w_adj,
                                               const float* __restrict__ b_adj,
                                               float* __restrict__ xchan) {
    __shared__ float wsh[18 * 256];
    int t = threadIdx.x;
    for (int i = t; i < 18 * 256; i += 128) wsh[i] = w_adj[i];
    __syncthreads();
    int gp  = blockIdx.x * 128 + t;
    int n   = gp >> 12;
    int pix = gp & 4095;
    const float* xp = x + (n << 20) + pix;
    float acc[18];
#pragma unroll
    for (int o = 0; o < 18; ++o) acc[o] = b_adj[o];
    for (int c = 0; c < 256; ++c) {
        float xv = xp[c << 12];
#pragma unroll
        for (int o = 0; o < 18; ++o) acc[o] = fmaf(xv, wsh[(o << 8) + c], acc[o]);
    }
    float* op = xchan + n * (18 * NPLANE) + pix;
#pragma unroll
    for (int o = 0; o < 18; ++o) op[o << 12] = acc[o];
}

// ---------------- depthwise 3x3 (groups=18), pad=1 ----------------
__global__ __launch_bounds__(256) void k_off(const float* __restrict__ xchan,
                                             const float* __restrict__ w_off,
                                             const float* __restrict__ b_off,
                                             float* __restrict__ off) {
    int idx = blockIdx.x * 256 + threadIdx.x;
    int pix = idx & 4095;
    int w = pix & 63, h = pix >> 6;
    int rest = idx >> 12;
    int oc = rest % 18;
    const float* wp  = w_off + oc * 9;
    const float* src = xchan + (idx & ~4095);
    float acc = b_off[oc];
#pragma unroll
    for (int i = 0; i < 3; ++i) {
        int hh = h - 1 + i;
        if ((unsigned)hh >= 64u) continue;
#pragma unroll
        for (int j = 0; j < 3; ++j) {
            int ww = w - 1 + j;
            if ((unsigned)ww >= 64u) continue;
            acc = fmaf(src[(hh << 6) + ww], wp[i * 3 + j], acc);
        }
    }
    off[idx] = acc;
}

// ---------------- weight -> MFMA A-fragment layout (bf16) ----------------
// wfrag[kstep][ct][lane][e]: cout = ct*16 + (lane&15); k32 = (lane>>4)*8 + e
__global__ __launch_bounds__(256) void k_wfrag(const float* __restrict__ w_def,
                                               ushort* __restrict__ wfrag) {
    int idx = blockIdx.x * 256 + threadIdx.x;   // over 589824
    int e     = idx & 7;
    int lane  = (idx >> 3) & 63;
    int ct    = (idx >> 9) & 15;
    int kstep = idx >> 13;
    int cout = ct * 16 + (lane & 15);
    int c    = ((kstep & 7) << 5) + ((lane >> 4) << 3) + e;
    int tap  = kstep >> 3;
    float v = w_def[cout * 2304 + c * 9 + tap];
    wfrag[idx] = (ushort)bf16_1(v);
}

// ---------------- corner-quad pack: 4 bf16 corners per 8B ----------------
// xq[nc][(y+1)*65 + (x+1)] = {v(y,x), v(y,x+1), v(y+1,x), v(y+1,x+1)}, 0 outside
__global__ __launch_bounds__(256) void k_pack(const float* __restrict__ x,
                                              uint2* __restrict__ xq) {
    int chunk = blockIdx.x % 17;        // 17*256 = 4352 >= 4225
    int nc    = blockIdx.x / 17;
    int r = chunk * 256 + threadIdx.x;
    if (r >= QPITCH) return;
    int yq = r / 65;
    int xb = r - yq * 65;
    int y = yq - 1, xx = xb - 1;
    const float* src = x + ((size_t)nc << 12);
    bool y0ok = (y >= 0);
    bool y1ok = (y < 63);
    bool x0ok = (xx >= 0);
    bool x1ok = (xx < 63);
    int ro = (y << 6) + xx;
    float v00 = (y0ok && x0ok) ? src[ro]      : 0.f;
    float v01 = (y0ok && x1ok) ? src[ro + 1]  : 0.f;
    float v10 = (y1ok && x0ok) ? src[ro + 64] : 0.f;
    float v11 = (y1ok && x1ok) ? src[ro + 65] : 0.f;
    uint2 q;
    q.x = bf16_pair(v00, v01);
    q.y = bf16_pair(v10, v11);
    xq[(size_t)nc * QPITCH + r] = q;
}

// ---------------- bilinear sampler (quad loads) -> col B-fragments -------
// col[nl][kstep][tile][lane][8]: pix = tile*16+(lane&15),
// c = (kstep&7)*32 + (lane>>4)*8 + e, tap = kstep>>3
__global__ __launch_bounds__(256) void k_sample(const uint2* __restrict__ xq,
                                                const float* __restrict__ off,
                                                ushort* __restrict__ col,
                                                int n_base) {
    int b = blockIdx.x;              // 4 * 72 * 64
    int nl = b / 4608;
    int r  = b - nl * 4608;
    int kstep = r >> 6;
    int tb    = r & 63;
    int t    = threadIdx.x;
    int tile = tb * 4 + (t >> 6);
    int lane = t & 63;
    int n = n_base + nl;

    int pix = tile * 16 + (lane & 15);
    int tap = kstep >> 3;
    int c0  = ((kstep & 7) << 5) + ((lane >> 4) << 3);

    const float* offp = off + (((n * 18 + 2 * tap) << 12) + pix);
    float oy = offp[0];
    float ox = offp[NPLANE];

    float py = (float)((pix >> 6) - 1 + tap / 3) + oy;
    float px = (float)((pix & 63) - 1 + tap % 3) + ox;
    float fy = floorf(py), fx = floorf(px);
    int y0 = (int)fy, x0 = (int)fx;
    float wy1 = py - fy, wx1 = px - fx;
    float ay0 = ((unsigned)y0       < 64u) ? 1.f - wy1 : 0.f;
    float ay1 = ((unsigned)(y0 + 1) < 64u) ? wy1 : 0.f;
    float ax0 = ((unsigned)x0       < 64u) ? 1.f - wx1 : 0.f;
    float ax1 = ((unsigned)(x0 + 1) < 64u) ? wx1 : 0.f;
    int yqi = min(max(y0, -1), 63) + 1;
    int xqi = min(max(x0, -1), 63) + 1;

    const uint2* qp = xq + (size_t)(n * 256 + c0) * QPITCH + yqi * 65 + xqi;
    unsigned rr[4];
#pragma unroll
    for (int e2 = 0; e2 < 4; ++e2) {
        uint2 q0 = qp[0]; qp += QPITCH;
        uint2 q1 = qp[0]; qp += QPITCH;
        float v0 = ay0 * fmaf(ax0, bl(q0.x), ax1 * bh(q0.x)) +
                   ay1 * fmaf(ax0, bl(q0.y), ax1 * bh(q0.y));
        float v1 = ay0 * fmaf(ax0, bl(q1.x), ax1 * bh(q1.x)) +
                   ay1 * fmaf(ax0, bl(q1.y), ax1 * bh(q1.y));
        rr[e2] = bf16_pair(v0, v1);
    }
    size_t frag = (size_t)(nl * 72 + kstep) * 256 + tile;
    *(uint4*)(col + frag * 512 + lane * 8) = make_uint4(rr[0], rr[1], rr[2], rr[3]);
}

// ---------------- MFMA GEMM: no LDS, no barriers ----------------
// block = 4 waves = 32 pix x 256 couts; wave = 32 pix x 64 couts, acc[2][4]
__global__ __launch_bounds__(256) void k_gemm(const ushort* __restrict__ col,
                                              const ushort* __restrict__ wfrag,
                                              float* __restrict__ out,
                                              int n_base) {
    int t = threadIdx.x;
    int wv = t >> 6, lane = t & 63;
    int nl = blockIdx.x >> 7;            // 0..3
    int tb = (blockIdx.x & 127) << 1;    // base 16-pix tile (2 per block)

    const ushort* ca = col + ((size_t)(nl * 72) * 256 + tb) * 512 + lane * 8;
    const ushort* wb = wfrag + (size_t)(wv * 4) * 512 + lane * 8;

    f32x4 acc[2][4] = {};

#pragma unroll 3
    for (int ks = 0; ks < 72; ++ks) {
        short8v a[2], bb[4];
        const ushort* cak = ca + (size_t)ks * (256 * 512);
        const ushort* wbk = wb + (size_t)ks * (16 * 512);
#pragma unroll
        for (int i = 0; i < 2; ++i) a[i]  = *(const short8v*)(cak + i * 512);
#pragma unroll
        for (int j = 0; j < 4; ++j) bb[j] = *(const short8v*)(wbk + j * 512);
#pragma unroll
        for (int i = 0; i < 2; ++i)
#pragma unroll
            for (int j = 0; j < 4; ++j)
                acc[i][j] = __builtin_amdgcn_mfma_f32_16x16x32_bf16(
                    bb[j], a[i], acc[i][j], 0, 0, 0);
    }

    // D layout: col = lane&15 (pix), row = (lane>>4)*4 + r (cout)
    int n = n_base + nl;
    int cl = lane & 15;
    int ch = (lane >> 4) << 2;
    float* outn = out + ((size_t)n << 20);
#pragma unroll
    for (int i = 0; i < 2; ++i) {
        int pix = ((tb + i) << 4) + cl;
#pragma unroll
        for (int j = 0; j < 4; ++j) {
            int cout = (wv << 6) + (j << 4) + ch;
            float* op = outn + ((size_t)cout << 12) + pix;
#pragma unroll
            for (int rr = 0; rr < 4; ++rr) op[(size_t)rr << 12] = acc[i][j][rr];
        }
    }
}

// ================= fallback fp32 path (ws too small) =================
__global__ __launch_bounds__(256) void k_reorder(const float* __restrict__ w_def,
                                                 float* __restrict__ w_t) {
    int idx = blockIdx.x * 256 + threadIdx.x;
    int co = idx & 255;
    int c  = (idx >> 8) & 255;
    int k  = idx >> 16;
    w_t[idx] = w_def[co * 2304 + c * 9 + k];
}

__global__ __launch_bounds__(256) void k_deform(const float* __restrict__ x,
                                                const float* __restrict__ off,
                                                const float* __restrict__ w_t,
                                                float* __restrict__ out) {
    __shared__ float colS[16][64];
    __shared__ float wS[16][128];
    __shared__ int   sy0[64], sx0[64];
    __shared__ float swy[64], swx[64];
    int t   = threadIdx.x;
    int n   = blockIdx.x >> 6;
    int h   = blockIdx.x & 63;
    int co0 = blockIdx.y << 7;
    float acc[4][8];
#pragma unroll
    for (int i = 0; i < 4; ++i)
#pragma unroll
        for (int j = 0; j < 8; ++j) acc[i][j] = 0.f;
    int tp = t & 15, tc = t >> 4;
    int cc_b = t >> 4, p0_b = (t & 15) << 2;
    const float* xn = x + (n << 20);
    for (int k = 0; k < 9; ++k) {
        if (t < 64) {
            const float* offp = off + ((n * 18 + 2 * k) << 12) + (h << 6);
            float oy = offp[t];
            float ox = offp[4096 + t];
            float py = (float)(h - 1 + k / 3) + oy;
            float px = (float)(t - 1 + k % 3) + ox;
            float fy = floorf(py), fx = floorf(px);
            sy0[t] = (int)fy; sx0[t] = (int)fx;
            swy[t] = py - fy; swx[t] = px - fx;
        }
        for (int c0 = 0; c0 < 256; c0 += 16) {
            __syncthreads();
            const float* base = xn + ((c0 + cc_b) << 12);
#pragma unroll
            for (int u = 0; u < 4; ++u) {
                int p = p0_b + u;
                int y0 = sy0[p], x0 = sx0[p];
                float wy = swy[p], wx = swx[p];
                float v00 = 0.f, v01 = 0.f, v10 = 0.f, v11 = 0.f;
                bool oky0 = (unsigned)y0 < 64u, oky1 = (unsigned)(y0 + 1) < 64u;
                bool okx0 = (unsigned)x0 < 64u, okx1 = (unsigned)(x0 + 1) < 64u;
                int r0 = (y0 << 6) + x0;
                if (oky0 && okx0) v00 = base[r0];
                if (oky0 && okx1) v01 = base[r0 + 1];
                if (oky1 && okx0) v10 = base[r0 + 64];
                if (oky1 && okx1) v11 = base[r0 + 65];
                colS[cc_b][p] = (v00 * (1.f - wx) + v01 * wx) * (1.f - wy) +
                                (v10 * (1.f - wx) + v11 * wx) * wy;
            }
            const float* wt = w_t + (k << 16) + (c0 << 8) + co0;
#pragma unroll
            for (int i = 0; i < 2; ++i) {
                int fi = i * 256 + t;
                int cc = fi >> 5;
                int cf = (fi & 31) << 2;
                *(float4*)&wS[cc][cf] = *(const float4*)&wt[(cc << 8) + cf];
            }
            __syncthreads();
#pragma unroll
            for (int kk = 0; kk < 16; ++kk) {
                float4 cv = *(const float4*)&colS[kk][tp << 2];
                float4 w0 = *(const float4*)&wS[kk][tc << 3];
                float4 w1 = *(const float4*)&wS[kk][(tc << 3) + 4];
                float cva[4] = {cv.x, cv.y, cv.z, cv.w};
                float wa[8]  = {w0.x, w0.y, w0.z, w0.w, w1.x, w1.y, w1.z, w1.w};
#pragma unroll
                for (int i = 0; i < 4; ++i)
#pragma unroll
                    for (int j = 0; j < 8; ++j)
                        acc[i][j] = fmaf(cva[i], wa[j], acc[i][j]);
            }
        }
    }
    int ob = (n << 20) + ((co0 + (tc << 3)) << 12) + (h << 6) + (tp << 2);
#pragma unroll
    for (int j = 0; j < 8; ++j) {
        float4 v = {acc[0][j], acc[1][j], acc[2][j], acc[3][j]};
        *(float4*)&out[ob + (j << 12)] = v;
    }
}

extern "C" void kernel_launch(void* const* d_in, const int* in_sizes, int n_in,
                              void* d_out, int out_size, void* d_ws, size_t ws_size,
                              hipStream_t stream) {
    const float* x     = (const float*)d_in[0];
    const float* w_adj = (const float*)d_in[1];
    const float* b_adj = (const float*)d_in[2];
    const float* w_off = (const float*)d_in[3];
    const float* b_off = (const float*)d_in[4];
    const float* w_def = (const float*)d_in[5];
    float* out = (float*)d_out;

    char* ws = (char*)d_ws;
    float* xchan = (float*)ws;                          // 2359296 B
    float* off   = (float*)(ws + 2359296);              // 2359296 B

    k_xchan<<<256, 128, 0, stream>>>(x, w_adj, b_adj, xchan);
    k_off<<<2304, 256, 0, stream>>>(xchan, w_off, b_off, off);

    const size_t NEED = 150618112;
    if (ws_size >= NEED) {
        ushort* wfrag = (ushort*)(ws + 4718592);        // 1179648 B
        uint2*  xquad = (uint2*)(ws + 5898240);         // 69222400 B
        ushort* col   = (ushort*)(ws + 75120640);       // 75497472 B
        k_wfrag<<<2304, 256, 0, stream>>>(w_def, wfrag);
        k_pack<<<2048 * 17, 256, 0, stream>>>(x, xquad);
        for (int hb = 0; hb < 2; ++hb) {
            k_sample<<<18432, 256, 0, stream>>>(xquad, off, col, hb * 4);
            k_gemm<<<512, 256, 0, stream>>>(col, wfrag, out, hb * 4);
        }
    } else {
        float* w_t = (float*)(ws + 4718592);
        k_reorder<<<2304, 256, 0, stream>>>(w_def, w_t);
        k_deform<<<dim3(512, 2), 256, 0, stream>>>(x, off, w_t, out);
    }
}

// Round 4
// 194.385 us; speedup vs baseline: 4.0013x; 1.3740x over previous
//
#include <hip/hip_runtime.h>

// Sizes (fixed):
// x: (8,256,64,64) f32 | w_adj: (18,256,1,1) | b_adj: (18)
// w_off: (18,1,3,3) | b_off: (18) | w_def: (256,256,3,3)
// out: (8,256,64,64) f32
//
// Implicit GEMM: out[cout][pix] = sum_{K=tap*256+c} W[cout][K] * col[K][pix]
// M=256, N=32768, K=2304 -> 38.7 GFLOP -> bf16 MFMA.
//
// ws layout (bytes):
//   xchan f32 : [0,        2359296)
//   off   f32 : [2359296,  4718592)
//   wfrag bf16: [4718592,  5898240)
//   xquad 8B  : [5898240,  75120640)   8n x 256c x 65 x 65 quads (padded border)
//   col   bf16: [75120640, 150618112)  HALF batch: 4n x 72ks x 256tiles x 64 x 8
// Batch processed in two halves (n 0..3, 4..7) to fit ws.
// Fallback (ws too small): fp32 path, w_t f32 at [4718592, 7077888).

typedef __attribute__((ext_vector_type(8))) short short8v;
typedef __attribute__((ext_vector_type(4))) float f32x4;

#define NPLANE 4096
#define QPITCH 4225   // 65*65

__device__ inline unsigned bf16_1(float a) {
    unsigned u = __float_as_uint(a);
    u += 0x7fffu + ((u >> 16) & 1u);
    return u >> 16;
}
__device__ inline unsigned bf16_pair(float a, float b) {
    unsigned ua = __float_as_uint(a); ua += 0x7fffu + ((ua >> 16) & 1u);
    unsigned ub = __float_as_uint(b); ub += 0x7fffu + ((ub >> 16) & 1u);
    return (ua >> 16) | (ub & 0xffff0000u);
}
__device__ inline float bl(unsigned u) { return __uint_as_float(u << 16); }
__device__ inline float bh(unsigned u) { return __uint_as_float(u & 0xffff0000u); }

// ---------------- 1x1 conv: split-K over 8 channel groups ----------------
// block = 256 thr = 32 pixels x 8 cgroups(32 ch); 1024 blocks.
__global__ __launch_bounds__(256) void k_xchan(const float* __restrict__ x,
                                               const float* __restrict__ w_adj,
                                               const float* __restrict__ b_adj,
                                               float* __restrict__ xchan) {
    __shared__ float wsh[256][18];      // [c][o] — lanes broadcast-read
    __shared__ float part[8][32][19];   // [g][pix][o], pad 19
    int t = threadIdx.x;
    for (int i = t; i < 18 * 256; i += 256) {
        int o = i >> 8, c = i & 255;    // w_adj[o][c]
        wsh[c][o] = w_adj[i];
    }
    __syncthreads();
    int n    = blockIdx.x >> 7;
    int pix0 = (blockIdx.x & 127) << 5;
    int p = t & 31, g = t >> 5;
    const float* xp = x + ((size_t)n << 20) + ((size_t)g << 17) + pix0 + p;
    float acc[18];
#pragma unroll
    for (int o = 0; o < 18; ++o) acc[o] = 0.f;
#pragma unroll 4
    for (int ci = 0; ci < 32; ++ci) {
        float xv = xp[(size_t)ci << 12];
        const float* wr = wsh[(g << 5) + ci];
#pragma unroll
        for (int o = 0; o < 18; ++o) acc[o] = fmaf(xv, wr[o], acc[o]);
    }
#pragma unroll
    for (int o = 0; o < 18; ++o) part[g][p][o] = acc[o];
    __syncthreads();
    for (int i = t; i < 576; i += 256) {
        int o = i >> 5, p2 = i & 31;
        float s = b_adj[o];
#pragma unroll
        for (int g2 = 0; g2 < 8; ++g2) s += part[g2][p2][o];
        xchan[((size_t)n * 18 + o) * NPLANE + pix0 + p2] = s;
    }
}

// ---------------- depthwise 3x3 (groups=18), pad=1 ----------------
__global__ __launch_bounds__(256) void k_off(const float* __restrict__ xchan,
                                             const float* __restrict__ w_off,
                                             const float* __restrict__ b_off,
                                             float* __restrict__ off) {
    int idx = blockIdx.x * 256 + threadIdx.x;
    int pix = idx & 4095;
    int w = pix & 63, h = pix >> 6;
    int rest = idx >> 12;
    int oc = rest % 18;
    const float* wp  = w_off + oc * 9;
    const float* src = xchan + (idx & ~4095);
    float acc = b_off[oc];
#pragma unroll
    for (int i = 0; i < 3; ++i) {
        int hh = h - 1 + i;
        if ((unsigned)hh >= 64u) continue;
#pragma unroll
        for (int j = 0; j < 3; ++j) {
            int ww = w - 1 + j;
            if ((unsigned)ww >= 64u) continue;
            acc = fmaf(src[(hh << 6) + ww], wp[i * 3 + j], acc);
        }
    }
    off[idx] = acc;
}

// ---------------- weight -> MFMA A-fragment layout (bf16) ----------------
__global__ __launch_bounds__(256) void k_wfrag(const float* __restrict__ w_def,
                                               ushort* __restrict__ wfrag) {
    int idx = blockIdx.x * 256 + threadIdx.x;   // over 589824
    int e     = idx & 7;
    int lane  = (idx >> 3) & 63;
    int ct    = (idx >> 9) & 15;
    int kstep = idx >> 13;
    int cout = ct * 16 + (lane & 15);
    int c    = ((kstep & 7) << 5) + ((lane >> 4) << 3) + e;
    int tap  = kstep >> 3;
    float v = w_def[cout * 2304 + c * 9 + tap];
    wfrag[idx] = (ushort)bf16_1(v);
}

// ---------------- corner-quad pack: 4 bf16 corners per 8B ----------------
__global__ __launch_bounds__(256) void k_pack(const float* __restrict__ x,
                                              uint2* __restrict__ xq) {
    int chunk = blockIdx.x % 17;        // 17*256 = 4352 >= 4225
    int nc    = blockIdx.x / 17;
    int r = chunk * 256 + threadIdx.x;
    if (r >= QPITCH) return;
    int yq = r / 65;
    int xb = r - yq * 65;
    int y = yq - 1, xx = xb - 1;
    const float* src = x + ((size_t)nc << 12);
    bool y0ok = (y >= 0);
    bool y1ok = (y < 63);
    bool x0ok = (xx >= 0);
    bool x1ok = (xx < 63);
    int ro = (y << 6) + xx;
    float v00 = (y0ok && x0ok) ? src[ro]      : 0.f;
    float v01 = (y0ok && x1ok) ? src[ro + 1]  : 0.f;
    float v10 = (y1ok && x0ok) ? src[ro + 64] : 0.f;
    float v11 = (y1ok && x1ok) ? src[ro + 65] : 0.f;
    uint2 q;
    q.x = bf16_pair(v00, v01);
    q.y = bf16_pair(v10, v11);
    xq[(size_t)nc * QPITCH + r] = q;
}

// ---------------- bilinear sampler (quad loads) -> col B-fragments -------
__global__ __launch_bounds__(256) void k_sample(const uint2* __restrict__ xq,
                                                const float* __restrict__ off,
                                                ushort* __restrict__ col,
                                                int n_base) {
    int b = blockIdx.x;              // 4 * 72 * 64
    int nl = b / 4608;
    int r  = b - nl * 4608;
    int kstep = r >> 6;
    int tb    = r & 63;
    int t    = threadIdx.x;
    int tile = tb * 4 + (t >> 6);
    int lane = t & 63;
    int n = n_base + nl;

    int pix = tile * 16 + (lane & 15);
    int tap = kstep >> 3;
    int c0  = ((kstep & 7) << 5) + ((lane >> 4) << 3);

    const float* offp = off + (((n * 18 + 2 * tap) << 12) + pix);
    float oy = offp[0];
    float ox = offp[NPLANE];

    float py = (float)((pix >> 6) - 1 + tap / 3) + oy;
    float px = (float)((pix & 63) - 1 + tap % 3) + ox;
    float fy = floorf(py), fx = floorf(px);
    int y0 = (int)fy, x0 = (int)fx;
    float wy1 = py - fy, wx1 = px - fx;
    float ay0 = ((unsigned)y0       < 64u) ? 1.f - wy1 : 0.f;
    float ay1 = ((unsigned)(y0 + 1) < 64u) ? wy1 : 0.f;
    float ax0 = ((unsigned)x0       < 64u) ? 1.f - wx1 : 0.f;
    float ax1 = ((unsigned)(x0 + 1) < 64u) ? wx1 : 0.f;
    int yqi = min(max(y0, -1), 63) + 1;
    int xqi = min(max(x0, -1), 63) + 1;

    const uint2* qp = xq + (size_t)(n * 256 + c0) * QPITCH + yqi * 65 + xqi;
    unsigned rr[4];
#pragma unroll
    for (int e2 = 0; e2 < 4; ++e2) {
        uint2 q0 = qp[0]; qp += QPITCH;
        uint2 q1 = qp[0]; qp += QPITCH;
        float v0 = ay0 * fmaf(ax0, bl(q0.x), ax1 * bh(q0.x)) +
                   ay1 * fmaf(ax0, bl(q0.y), ax1 * bh(q0.y));
        float v1 = ay0 * fmaf(ax0, bl(q1.x), ax1 * bh(q1.x)) +
                   ay1 * fmaf(ax0, bl(q1.y), ax1 * bh(q1.y));
        rr[e2] = bf16_pair(v0, v1);
    }
    size_t frag = (size_t)(nl * 72 + kstep) * 256 + tile;
    *(uint4*)(col + frag * 512 + lane * 8) = make_uint4(rr[0], rr[1], rr[2], rr[3]);
}

// ---------------- MFMA GEMM: no LDS, no barriers ----------------
__global__ __launch_bounds__(256) void k_gemm(const ushort* __restrict__ col,
                                              const ushort* __restrict__ wfrag,
                                              float* __restrict__ out,
                                              int n_base) {
    int t = threadIdx.x;
    int wv = t >> 6, lane = t & 63;
    int nl = blockIdx.x >> 7;            // 0..3
    int tb = (blockIdx.x & 127) << 1;    // base 16-pix tile (2 per block)

    const ushort* ca = col + ((size_t)(nl * 72) * 256 + tb) * 512 + lane * 8;
    const ushort* wb = wfrag + (size_t)(wv * 4) * 512 + lane * 8;

    f32x4 acc[2][4] = {};

#pragma unroll 3
    for (int ks = 0; ks < 72; ++ks) {
        short8v a[2], bb[4];
        const ushort* cak = ca + (size_t)ks * (256 * 512);
        const ushort* wbk = wb + (size_t)ks * (16 * 512);
#pragma unroll
        for (int i = 0; i < 2; ++i) a[i]  = *(const short8v*)(cak + i * 512);
#pragma unroll
        for (int j = 0; j < 4; ++j) bb[j] = *(const short8v*)(wbk + j * 512);
#pragma unroll
        for (int i = 0; i < 2; ++i)
#pragma unroll
            for (int j = 0; j < 4; ++j)
                acc[i][j] = __builtin_amdgcn_mfma_f32_16x16x32_bf16(
                    bb[j], a[i], acc[i][j], 0, 0, 0);
    }

    int n = n_base + nl;
    int cl = lane & 15;
    int ch = (lane >> 4) << 2;
    float* outn = out + ((size_t)n << 20);
#pragma unroll
    for (int i = 0; i < 2; ++i) {
        int pix = ((tb + i) << 4) + cl;
#pragma unroll
        for (int j = 0; j < 4; ++j) {
            int cout = (wv << 6) + (j << 4) + ch;
            float* op = outn + ((size_t)cout << 12) + pix;
#pragma unroll
            for (int rr = 0; rr < 4; ++rr) op[(size_t)rr << 12] = acc[i][j][rr];
        }
    }
}

// ================= fallback fp32 path (ws too small) =================
__global__ __launch_bounds__(256) void k_reorder(const float* __restrict__ w_def,
                                                 float* __restrict__ w_t) {
    int idx = blockIdx.x * 256 + threadIdx.x;
    int co = idx & 255;
    int c  = (idx >> 8) & 255;
    int k  = idx >> 16;
    w_t[idx] = w_def[co * 2304 + c * 9 + k];
}

__global__ __launch_bounds__(256) void k_deform(const float* __restrict__ x,
                                                const float* __restrict__ off,
                                                const float* __restrict__ w_t,
                                                float* __restrict__ out) {
    __shared__ float colS[16][64];
    __shared__ float wS[16][128];
    __shared__ int   sy0[64], sx0[64];
    __shared__ float swy[64], swx[64];
    int t   = threadIdx.x;
    int n   = blockIdx.x >> 6;
    int h   = blockIdx.x & 63;
    int co0 = blockIdx.y << 7;
    float acc[4][8];
#pragma unroll
    for (int i = 0; i < 4; ++i)
#pragma unroll
        for (int j = 0; j < 8; ++j) acc[i][j] = 0.f;
    int tp = t & 15, tc = t >> 4;
    int cc_b = t >> 4, p0_b = (t & 15) << 2;
    const float* xn = x + (n << 20);
    for (int k = 0; k < 9; ++k) {
        if (t < 64) {
            const float* offp = off + ((n * 18 + 2 * k) << 12) + (h << 6);
            float oy = offp[t];
            float ox = offp[4096 + t];
            float py = (float)(h - 1 + k / 3) + oy;
            float px = (float)(t - 1 + k % 3) + ox;
            float fy = floorf(py), fx = floorf(px);
            sy0[t] = (int)fy; sx0[t] = (int)fx;
            swy[t] = py - fy; swx[t] = px - fx;
        }
        for (int c0 = 0; c0 < 256; c0 += 16) {
            __syncthreads();
            const float* base = xn + ((c0 + cc_b) << 12);
#pragma unroll
            for (int u = 0; u < 4; ++u) {
                int p = p0_b + u;
                int y0 = sy0[p], x0 = sx0[p];
                float wy = swy[p], wx = swx[p];
                float v00 = 0.f, v01 = 0.f, v10 = 0.f, v11 = 0.f;
                bool oky0 = (unsigned)y0 < 64u, oky1 = (unsigned)(y0 + 1) < 64u;
                bool okx0 = (unsigned)x0 < 64u, okx1 = (unsigned)(x0 + 1) < 64u;
                int r0 = (y0 << 6) + x0;
                if (oky0 && okx0) v00 = base[r0];
                if (oky0 && okx1) v01 = base[r0 + 1];
                if (oky1 && okx0) v10 = base[r0 + 64];
                if (oky1 && okx1) v11 = base[r0 + 65];
                colS[cc_b][p] = (v00 * (1.f - wx) + v01 * wx) * (1.f - wy) +
                                (v10 * (1.f - wx) + v11 * wx) * wy;
            }
            const float* wt = w_t + (k << 16) + (c0 << 8) + co0;
#pragma unroll
            for (int i = 0; i < 2; ++i) {
                int fi = i * 256 + t;
                int cc = fi >> 5;
                int cf = (fi & 31) << 2;
                *(float4*)&wS[cc][cf] = *(const float4*)&wt[(cc << 8) + cf];
            }
            __syncthreads();
#pragma unroll
            for (int kk = 0; kk < 16; ++kk) {
                float4 cv = *(const float4*)&colS[kk][tp << 2];
                float4 w0 = *(const float4*)&wS[kk][tc << 3];
                float4 w1 = *(const float4*)&wS[kk][(tc << 3) + 4];
                float cva[4] = {cv.x, cv.y, cv.z, cv.w};
                float wa[8]  = {w0.x, w0.y, w0.z, w0.w, w1.x, w1.y, w1.z, w1.w};
#pragma unroll
                for (int i = 0; i < 4; ++i)
#pragma unroll
                    for (int j = 0; j < 8; ++j)
                        acc[i][j] = fmaf(cva[i], wa[j], acc[i][j]);
            }
        }
    }
    int ob = (n << 20) + ((co0 + (tc << 3)) << 12) + (h << 6) + (tp << 2);
#pragma unroll
    for (int j = 0; j < 8; ++j) {
        float4 v = {acc[0][j], acc[1][j], acc[2][j], acc[3][j]};
        *(float4*)&out[ob + (j << 12)] = v;
    }
}

extern "C" void kernel_launch(void* const* d_in, const int* in_sizes, int n_in,
                              void* d_out, int out_size, void* d_ws, size_t ws_size,
                              hipStream_t stream) {
    const float* x     = (const float*)d_in[0];
    const float* w_adj = (const float*)d_in[1];
    const float* b_adj = (const float*)d_in[2];
    const float* w_off = (const float*)d_in[3];
    const float* b_off = (const float*)d_in[4];
    const float* w_def = (const float*)d_in[5];
    float* out = (float*)d_out;

    char* ws = (char*)d_ws;
    float* xchan = (float*)ws;                          // 2359296 B
    float* off   = (float*)(ws + 2359296);              // 2359296 B

    k_xchan<<<1024, 256, 0, stream>>>(x, w_adj, b_adj, xchan);
    k_off<<<2304, 256, 0, stream>>>(xchan, w_off, b_off, off);

    const size_t NEED = 150618112;
    if (ws_size >= NEED) {
        ushort* wfrag = (ushort*)(ws + 4718592);        // 1179648 B
        uint2*  xquad = (uint2*)(ws + 5898240);         // 69222400 B
        ushort* col   = (ushort*)(ws + 75120640);       // 75497472 B
        k_wfrag<<<2304, 256, 0, stream>>>(w_def, wfrag);
        k_pack<<<2048 * 17, 256, 0, stream>>>(x, xquad);
        for (int hb = 0; hb < 2; ++hb) {
            k_sample<<<18432, 256, 0, stream>>>(xquad, off, col, hb * 4);
            k_gemm<<<512, 256, 0, stream>>>(col, wfrag, out, hb * 4);
        }
    } else {
        float* w_t = (float*)(ws + 4718592);
        k_reorder<<<2304, 256, 0, stream>>>(w_def, w_t);
        k_deform<<<dim3(512, 2), 256, 0, stream>>>(x, off, w_t, out);
    }
}

// Round 5
// 122.812 us; speedup vs baseline: 6.3332x; 1.5828x over previous
//
#include <hip/hip_runtime.h>

// Sizes (fixed):
// x: (8,256,64,64) f32 | w_adj: (18,256,1,1) | b_adj: (18)
// w_off: (18,1,3,3) | b_off: (18) | w_def: (256,256,3,3)
// out: (8,256,64,64) f32
//
// Implicit GEMM: out[cout][pix] = sum_{K=tap*256+c} W[cout][K] * col[K][pix]
// M=256, N=32768, K=2304 -> 38.7 GFLOP -> bf16 MFMA.
// Round 5: sampler fused into the GEMM (col never hits HBM);
// x pre-transposed to [n][pix][c] bf16 so 8 channels = one 16B gather.
//
// ws layout (bytes):
//   xchan f32 : [0,        2359296)
//   off   f32 : [2359296,  4718592)
//   wfrag bf16: [4718592,  5898240)
//   xT    bf16: [5898240,  22675456)   8n x 4096pix x 256c
// Fallback (ws too small): fp32 path, w_t f32 at [4718592, 7077888).

typedef __attribute__((ext_vector_type(8))) short short8v;
typedef __attribute__((ext_vector_type(4))) float f32x4;

#define NPLANE 4096

__device__ inline unsigned bf16_1(float a) {
    unsigned u = __float_as_uint(a);
    u += 0x7fffu + ((u >> 16) & 1u);
    return u >> 16;
}
__device__ inline unsigned bf16_pair(float a, float b) {
    unsigned ua = __float_as_uint(a); ua += 0x7fffu + ((ua >> 16) & 1u);
    unsigned ub = __float_as_uint(b); ub += 0x7fffu + ((ub >> 16) & 1u);
    return (ua >> 16) | (ub & 0xffff0000u);
}
__device__ inline float bl(unsigned u) { return __uint_as_float(u << 16); }
__device__ inline float bh(unsigned u) { return __uint_as_float(u & 0xffff0000u); }

// ---------------- 1x1 conv: split-K over 8 channel groups ----------------
__global__ __launch_bounds__(256) void k_xchan(const float* __restrict__ x,
                                               const float* __restrict__ w_adj,
                                               const float* __restrict__ b_adj,
                                               float* __restrict__ xchan) {
    __shared__ float wsh[256][18];
    __shared__ float part[8][32][19];
    int t = threadIdx.x;
    for (int i = t; i < 18 * 256; i += 256) {
        int o = i >> 8, c = i & 255;
        wsh[c][o] = w_adj[i];
    }
    __syncthreads();
    int n    = blockIdx.x >> 7;
    int pix0 = (blockIdx.x & 127) << 5;
    int p = t & 31, g = t >> 5;
    const float* xp = x + ((size_t)n << 20) + ((size_t)g << 17) + pix0 + p;
    float acc[18];
#pragma unroll
    for (int o = 0; o < 18; ++o) acc[o] = 0.f;
#pragma unroll 4
    for (int ci = 0; ci < 32; ++ci) {
        float xv = xp[(size_t)ci << 12];
        const float* wr = wsh[(g << 5) + ci];
#pragma unroll
        for (int o = 0; o < 18; ++o) acc[o] = fmaf(xv, wr[o], acc[o]);
    }
#pragma unroll
    for (int o = 0; o < 18; ++o) part[g][p][o] = acc[o];
    __syncthreads();
    for (int i = t; i < 576; i += 256) {
        int o = i >> 5, p2 = i & 31;
        float s = b_adj[o];
#pragma unroll
        for (int g2 = 0; g2 < 8; ++g2) s += part[g2][p2][o];
        xchan[((size_t)n * 18 + o) * NPLANE + pix0 + p2] = s;
    }
}

// ---------------- depthwise 3x3 (groups=18), pad=1 ----------------
__global__ __launch_bounds__(256) void k_off(const float* __restrict__ xchan,
                                             const float* __restrict__ w_off,
                                             const float* __restrict__ b_off,
                                             float* __restrict__ off) {
    int idx = blockIdx.x * 256 + threadIdx.x;
    int pix = idx & 4095;
    int w = pix & 63, h = pix >> 6;
    int rest = idx >> 12;
    int oc = rest % 18;
    const float* wp  = w_off + oc * 9;
    const float* src = xchan + (idx & ~4095);
    float acc = b_off[oc];
#pragma unroll
    for (int i = 0; i < 3; ++i) {
        int hh = h - 1 + i;
        if ((unsigned)hh >= 64u) continue;
#pragma unroll
        for (int j = 0; j < 3; ++j) {
            int ww = w - 1 + j;
            if ((unsigned)ww >= 64u) continue;
            acc = fmaf(src[(hh << 6) + ww], wp[i * 3 + j], acc);
        }
    }
    off[idx] = acc;
}

// ---------------- weight -> MFMA A-fragment layout (bf16) ----------------
// wfrag element idx = ((kstep*16 + ct)*64 + lane)*8 + e
// cout = ct*16 + (lane&15); c = (kstep&7)*32 + (lane>>4)*8 + e; tap = kstep>>3
__global__ __launch_bounds__(256) void k_wfrag(const float* __restrict__ w_def,
                                               ushort* __restrict__ wfrag) {
    int idx = blockIdx.x * 256 + threadIdx.x;   // over 589824
    int e     = idx & 7;
    int lane  = (idx >> 3) & 63;
    int ct    = (idx >> 9) & 15;
    int kstep = idx >> 13;
    int cout = ct * 16 + (lane & 15);
    int c    = ((kstep & 7) << 5) + ((lane >> 4) << 3) + e;
    int tap  = kstep >> 3;
    float v = w_def[cout * 2304 + c * 9 + tap];
    wfrag[idx] = (ushort)bf16_1(v);
}

// ---------------- transpose: x (n,c,pix) f32 -> xT (n,pix,c) bf16 --------
// block: 64 channels x 64 pixels tile via LDS; grid = 8n * 4cg * 64pg
__global__ __launch_bounds__(256) void k_trans(const float* __restrict__ x,
                                               ushort* __restrict__ xT) {
    __shared__ unsigned tileU[64][35];   // [pix][c/2], pad 35 (conflict-free)
    int b  = blockIdx.x;
    int pg = b & 63;
    int cg = (b >> 6) & 3;
    int n  = b >> 8;
    int t  = threadIdx.x;
    // stage: thread (pl = t&63, c4 = t>>6) loads 16 channels at its pixel
    int pl = t & 63, c4 = t >> 6;
    const float* src = x + (((size_t)(n * 256 + cg * 64 + c4 * 16)) << 12)
                         + (pg << 6) + pl;
#pragma unroll
    for (int i2 = 0; i2 < 8; ++i2) {
        float f0 = src[(size_t)(2 * i2) << 12];
        float f1 = src[(size_t)(2 * i2 + 1) << 12];
        tileU[pl][c4 * 8 + i2] = bf16_pair(f0, f1);
    }
    __syncthreads();
    // write: thread (cl2 = t&31, pr = t>>5): 8 rows, coalesced uint stores
    int cl2 = t & 31, pr = t >> 5;
    unsigned* dst = (unsigned*)xT;
#pragma unroll
    for (int i = 0; i < 8; ++i) {
        int p2 = pr + (i << 3);
        dst[((size_t)(n << 12) + (pg << 6) + p2) * 128 + (cg << 5) + cl2] =
            tileU[p2][cl2];
    }
}

// ---------------- fused sampler + MFMA GEMM ----------------
// block = 4 waves = 64 px (4 frag tiles) x 256 couts; grid = 8n x 64 tq = 512
// per kstep: 256 thr sample 32ch x 64px into colS (dbuf), 1 barrier,
// each wave: 4 ds_read_b128 A-frags + 4 global B-frags -> 16 MFMA.
__global__ __launch_bounds__(256) void k_fused(const ushort* __restrict__ xT,
                                               const float* __restrict__ off,
                                               const ushort* __restrict__ wfrag,
                                               float* __restrict__ out) {
    __shared__ ushort colS[2][4][64][8];   // 8 KB, double-buffered

    int t = threadIdx.x;
    int wv = t >> 6, lane = t & 63;
    int n  = blockIdx.x >> 6;
    int tq = blockIdx.x & 63;

    int plo  = lane & 15;
    int spix = (tq << 6) + (wv << 4) + plo;   // this thread's sample pixel
    int sc   = (lane >> 4) << 3;              // channel offset in 32-group
    int sy = spix >> 6, sx = spix & 63;

    // preload offsets for all 9 taps (compile-time indexed -> registers)
    float oy[9], ox[9];
    const float* offn = off + (((size_t)n * 18) << 12) + spix;
#pragma unroll
    for (int tp = 0; tp < 9; ++tp) {
        oy[tp] = offn[(size_t)(2 * tp) << 12];
        ox[tp] = offn[(size_t)(2 * tp + 1) << 12];
    }

    const ushort* xTn = xT + (((size_t)n) << 12) * 256;

    float w00, w01, w10, w11;
    unsigned oA, oB, oC, oD;    // element offsets into xTn for corner gathers

    auto tap_setup = [&](int tp) {
        float py = (float)(sy - 1 + tp / 3) + oy[tp];
        float px = (float)(sx - 1 + tp % 3) + ox[tp];
        float fy = floorf(py), fx = floorf(px);
        int y0 = (int)fy, x0 = (int)fx;
        float wy1 = py - fy, wx1 = px - fx;
        float ay0 = ((unsigned)y0       < 64u) ? 1.f - wy1 : 0.f;
        float ay1 = ((unsigned)(y0 + 1) < 64u) ? wy1 : 0.f;
        float ax0 = ((unsigned)x0       < 64u) ? 1.f - wx1 : 0.f;
        float ax1 = ((unsigned)(x0 + 1) < 64u) ? wx1 : 0.f;
        w00 = ay0 * ax0; w01 = ay0 * ax1; w10 = ay1 * ax0; w11 = ay1 * ax1;
        int yc0 = min(max(y0, 0), 63), yc1 = min(max(y0 + 1, 0), 63);
        int xc0 = min(max(x0, 0), 63), xc1 = min(max(x0 + 1, 0), 63);
        oA = (unsigned)((((yc0 << 6) + xc0) << 8) + sc);
        oB = (unsigned)((((yc0 << 6) + xc1) << 8) + sc);
        oC = (unsigned)((((yc1 << 6) + xc0) << 8) + sc);
        oD = (unsigned)((((yc1 << 6) + xc1) << 8) + sc);
    };

    auto interp_write = [&](int nb, uint4 A, uint4 B, uint4 C, uint4 D) {
        unsigned qa[4] = {A.x, A.y, A.z, A.w};
        unsigned qb[4] = {B.x, B.y, B.z, B.w};
        unsigned qc[4] = {C.x, C.y, C.z, C.w};
        unsigned qd[4] = {D.x, D.y, D.z, D.w};
        unsigned rr[4];
#pragma unroll
        for (int i = 0; i < 4; ++i) {
            float v0 = w00 * bl(qa[i]) + w01 * bl(qb[i]) +
                       w10 * bl(qc[i]) + w11 * bl(qd[i]);
            float v1 = w00 * bh(qa[i]) + w01 * bh(qb[i]) +
                       w10 * bh(qc[i]) + w11 * bh(qd[i]);
            rr[i] = bf16_pair(v0, v1);
        }
        *(uint4*)&colS[nb][wv][lane][0] = make_uint4(rr[0], rr[1], rr[2], rr[3]);
    };

    f32x4 acc[4][4] = {};

    // prologue: sample kstep 0 into buffer 0
    tap_setup(0);
    {
        uint4 A = *(const uint4*)(xTn + oA);
        uint4 B = *(const uint4*)(xTn + oB);
        uint4 C = *(const uint4*)(xTn + oC);
        uint4 D = *(const uint4*)(xTn + oD);
        interp_write(0, A, B, C, D);
    }
    __syncthreads();

#pragma unroll
    for (int tap = 0; tap < 9; ++tap) {
#pragma unroll 1
        for (int kc = 0; kc < 8; ++kc) {
            const int ks  = tap * 8 + kc;
            const int cur = ks & 1;
            const bool have = (kc < 7) || (tap < 8);
            uint4 A = {0,0,0,0}, B = {0,0,0,0}, C = {0,0,0,0}, D = {0,0,0,0};
            if (kc < 7) {
                unsigned d = (unsigned)((kc + 1) << 5);
                A = *(const uint4*)(xTn + oA + d);
                B = *(const uint4*)(xTn + oB + d);
                C = *(const uint4*)(xTn + oC + d);
                D = *(const uint4*)(xTn + oD + d);
            } else if (tap < 8) {
                tap_setup(tap + 1);     // compile-time tap index
                A = *(const uint4*)(xTn + oA);
                B = *(const uint4*)(xTn + oB);
                C = *(const uint4*)(xTn + oC);
                D = *(const uint4*)(xTn + oD);
            }
            // A-fragments from LDS
            short8v a[4];
#pragma unroll
            for (int i = 0; i < 4; ++i)
                a[i] = *(const short8v*)&colS[cur][i][lane][0];
            // B-fragments (weights) from L2-resident wfrag
            const ushort* wbk = wfrag + ((size_t)ks * 16 + (wv << 2)) * 512
                                       + (lane << 3);
            short8v bb[4];
#pragma unroll
            for (int j = 0; j < 4; ++j)
                bb[j] = *(const short8v*)(wbk + (size_t)j * 512);
#pragma unroll
            for (int i = 0; i < 4; ++i)
#pragma unroll
                for (int j = 0; j < 4; ++j)
                    acc[i][j] = __builtin_amdgcn_mfma_f32_16x16x32_bf16(
                        bb[j], a[i], acc[i][j], 0, 0, 0);
            if (have) interp_write(cur ^ 1, A, B, C, D);
            __syncthreads();
        }
    }

    // epilogue: D layout col = lane&15 (pix), row = (lane>>4)*4 + r (cout)
    int cl = lane & 15;
    int ch = (lane >> 4) << 2;
    float* outn = out + ((size_t)n << 20);
#pragma unroll
    for (int i = 0; i < 4; ++i) {
        int pix = (tq << 6) + (i << 4) + cl;
#pragma unroll
        for (int j = 0; j < 4; ++j) {
            int cout = (wv << 6) + (j << 4) + ch;
            float* op = outn + ((size_t)cout << 12) + pix;
#pragma unroll
            for (int rr = 0; rr < 4; ++rr) op[(size_t)rr << 12] = acc[i][j][rr];
        }
    }
}

// ================= fallback fp32 path (ws too small) =================
__global__ __launch_bounds__(256) void k_reorder(const float* __restrict__ w_def,
                                                 float* __restrict__ w_t) {
    int idx = blockIdx.x * 256 + threadIdx.x;
    int co = idx & 255;
    int c  = (idx >> 8) & 255;
    int k  = idx >> 16;
    w_t[idx] = w_def[co * 2304 + c * 9 + k];
}

__global__ __launch_bounds__(256) void k_deform(const float* __restrict__ x,
                                                const float* __restrict__ off,
                                                const float* __restrict__ w_t,
                                                float* __restrict__ out) {
    __shared__ float colS[16][64];
    __shared__ float wS[16][128];
    __shared__ int   sy0[64], sx0[64];
    __shared__ float swy[64], swx[64];
    int t   = threadIdx.x;
    int n   = blockIdx.x >> 6;
    int h   = blockIdx.x & 63;
    int co0 = blockIdx.y << 7;
    float acc[4][8];
#pragma unroll
    for (int i = 0; i < 4; ++i)
#pragma unroll
        for (int j = 0; j < 8; ++j) acc[i][j] = 0.f;
    int tp = t & 15, tc = t >> 4;
    int cc_b = t >> 4, p0_b = (t & 15) << 2;
    const float* xn = x + (n << 20);
    for (int k = 0; k < 9; ++k) {
        if (t < 64) {
            const float* offp = off + ((n * 18 + 2 * k) << 12) + (h << 6);
            float oyv = offp[t];
            float oxv = offp[4096 + t];
            float py = (float)(h - 1 + k / 3) + oyv;
            float px = (float)(t - 1 + k % 3) + oxv;
            float fy = floorf(py), fx = floorf(px);
            sy0[t] = (int)fy; sx0[t] = (int)fx;
            swy[t] = py - fy; swx[t] = px - fx;
        }
        for (int c0 = 0; c0 < 256; c0 += 16) {
            __syncthreads();
            const float* base = xn + ((c0 + cc_b) << 12);
#pragma unroll
            for (int u = 0; u < 4; ++u) {
                int p = p0_b + u;
                int y0 = sy0[p], x0 = sx0[p];
                float wy = swy[p], wx = swx[p];
                float v00 = 0.f, v01 = 0.f, v10 = 0.f, v11 = 0.f;
                bool oky0 = (unsigned)y0 < 64u, oky1 = (unsigned)(y0 + 1) < 64u;
                bool okx0 = (unsigned)x0 < 64u, okx1 = (unsigned)(x0 + 1) < 64u;
                int r0 = (y0 << 6) + x0;
                if (oky0 && okx0) v00 = base[r0];
                if (oky0 && okx1) v01 = base[r0 + 1];
                if (oky1 && okx0) v10 = base[r0 + 64];
                if (oky1 && okx1) v11 = base[r0 + 65];
                colS[cc_b][p] = (v00 * (1.f - wx) + v01 * wx) * (1.f - wy) +
                                (v10 * (1.f - wx) + v11 * wx) * wy;
            }
            const float* wt = w_t + (k << 16) + (c0 << 8) + co0;
#pragma unroll
            for (int i = 0; i < 2; ++i) {
                int fi = i * 256 + t;
                int cc = fi >> 5;
                int cf = (fi & 31) << 2;
                *(float4*)&wS[cc][cf] = *(const float4*)&wt[(cc << 8) + cf];
            }
            __syncthreads();
#pragma unroll
            for (int kk = 0; kk < 16; ++kk) {
                float4 cv = *(const float4*)&colS[kk][tp << 2];
                float4 w0 = *(const float4*)&wS[kk][tc << 3];
                float4 w1 = *(const float4*)&wS[kk][(tc << 3) + 4];
                float cva[4] = {cv.x, cv.y, cv.z, cv.w};
                float wa[8]  = {w0.x, w0.y, w0.z, w0.w, w1.x, w1.y, w1.z, w1.w};
#pragma unroll
                for (int i = 0; i < 4; ++i)
#pragma unroll
                    for (int j = 0; j < 8; ++j)
                        acc[i][j] = fmaf(cva[i], wa[j], acc[i][j]);
            }
        }
    }
    int ob = (n << 20) + ((co0 + (tc << 3)) << 12) + (h << 6) + (tp << 2);
#pragma unroll
    for (int j = 0; j < 8; ++j) {
        float4 v = {acc[0][j], acc[1][j], acc[2][j], acc[3][j]};
        *(float4*)&out[ob + (j << 12)] = v;
    }
}

extern "C" void kernel_launch(void* const* d_in, const int* in_sizes, int n_in,
                              void* d_out, int out_size, void* d_ws, size_t ws_size,
                              hipStream_t stream) {
    const float* x     = (const float*)d_in[0];
    const float* w_adj = (const float*)d_in[1];
    const float* b_adj = (const float*)d_in[2];
    const float* w_off = (const float*)d_in[3];
    const float* b_off = (const float*)d_in[4];
    const float* w_def = (const float*)d_in[5];
    float* out = (float*)d_out;

    char* ws = (char*)d_ws;
    float* xchan = (float*)ws;                          // 2359296 B
    float* off   = (float*)(ws + 2359296);              // 2359296 B

    k_xchan<<<1024, 256, 0, stream>>>(x, w_adj, b_adj, xchan);
    k_off<<<2304, 256, 0, stream>>>(xchan, w_off, b_off, off);

    const size_t NEED = 22675456;
    if (ws_size >= NEED) {
        ushort* wfrag = (ushort*)(ws + 4718592);        // 1179648 B
        ushort* xT    = (ushort*)(ws + 5898240);        // 16777216 B
        k_wfrag<<<2304, 256, 0, stream>>>(w_def, wfrag);
        k_trans<<<2048, 256, 0, stream>>>(x, xT);
        k_fused<<<512, 256, 0, stream>>>(xT, off, wfrag, out);
    } else {
        float* w_t = (float*)(ws + 4718592);
        k_reorder<<<2304, 256, 0, stream>>>(w_def, w_t);
        k_deform<<<dim3(512, 2), 256, 0, stream>>>(x, off, w_t, out);
    }
}